// Round 11
// baseline (246.507 us; speedup 1.0000x reference)
//
#include <hip/hip_runtime.h>
#include <hip/hip_bf16.h>

#define C1 256
#define C2 512
#define NSP 3136   // 56*56
#define NT 98      // KV tiles of 32
#define LOG2E 1.44269504f
#define THR2 11.5453f   // 8 nats in base-2 units

typedef __attribute__((ext_vector_type(8))) short bf16x8;
typedef __attribute__((ext_vector_type(4))) float f32x4;

__device__ __forceinline__ ushort f2b(float f) {
  __hip_bfloat16 h = __float2bfloat16(f);
  return *reinterpret_cast<ushort*>(&h);
}
__device__ __forceinline__ float b2f(ushort u) {
  union { unsigned int i; float f; } v; v.i = ((unsigned int)u) << 16; return v.f;
}
__device__ __forceinline__ void gload16(const ushort* g, ushort* l) {
  __builtin_amdgcn_global_load_lds(
      (const __attribute__((address_space(1))) void*)g,
      (__attribute__((address_space(3))) void*)l, 16, 0, 0);
}
__device__ __forceinline__ void block_bar() {
  asm volatile("" ::: "memory");
  __builtin_amdgcn_s_barrier();
  asm volatile("" ::: "memory");
}

// ---- K0: Wf[ot16][cc][lane][8] = bf16 A-frag pack of W[o][c] ----------
__global__ __launch_bounds__(256) void k_wtf(const float* __restrict__ W,
                                             ushort* __restrict__ Wf) {
  int ot = blockIdx.x;            // 16
  int tid = threadIdx.x;
  int lane = tid & 63, l15 = lane & 15, g = (lane >> 4) & 3;
  int cc0 = (tid >> 6) * 4;
  const float* src = W + (size_t)(ot * 16 + l15) * C2 + g * 8;
#pragma unroll
  for (int k = 0; k < 4; k++) {
    int cc = cc0 + k;
    float4 u0 = *reinterpret_cast<const float4*>(src + cc * 32);
    float4 u1 = *reinterpret_cast<const float4*>(src + cc * 32 + 4);
    bf16x8 v;
    v[0] = (short)f2b(u0.x); v[1] = (short)f2b(u0.y);
    v[2] = (short)f2b(u0.z); v[3] = (short)f2b(u0.w);
    v[4] = (short)f2b(u1.x); v[5] = (short)f2b(u1.y);
    v[6] = (short)f2b(u1.z); v[7] = (short)f2b(u1.w);
    *reinterpret_cast<bf16x8*>(Wf + ((size_t)(ot * 16 + cc)) * 512 + lane * 8) = v;
  }
}

// ---- K1: x1t[b][n][c] = bf16(LOG2E * x1[b][c][n])  (Q pre-scaled) -----
__global__ __launch_bounds__(256) void k_x1t(const float* __restrict__ x1,
                                             ushort* __restrict__ x1t) {
  __shared__ float t[32][33];
  int b = blockIdx.z;
  int n0 = blockIdx.x * 32;
  int c0 = blockIdx.y * 32;
  int tid = threadIdx.x;
  int r = tid >> 3, q = (tid & 7) * 4;
  const float* src = x1 + ((size_t)b * C1 + (c0 + r)) * NSP + n0 + q;
  float4 v = *reinterpret_cast<const float4*>(src);
  t[r][q] = v.x; t[r][q + 1] = v.y; t[r][q + 2] = v.z; t[r][q + 3] = v.w;
  __syncthreads();
  ushort4 o;
  o.x = f2b(t[q + 0][r] * LOG2E); o.y = f2b(t[q + 1][r] * LOG2E);
  o.z = f2b(t[q + 2][r] * LOG2E); o.w = f2b(t[q + 3][r] * LOG2E);
  *reinterpret_cast<ushort4*>(x1t + ((size_t)b * NSP + n0 + r) * C1 + c0 + q) = o;
}

// ---- K2: x2f[b][nt16][cc][lane][8] = bf16 B-frag pack of x2[b][c][n] --
__global__ __launch_bounds__(256) void k_x2f(const float* __restrict__ x2,
                                             ushort* __restrict__ x2f) {
  __shared__ float t[32][33];
  int b = blockIdx.z;
  int n0 = blockIdx.x * 32;   // 98
  int cc = blockIdx.y;        // 16
  int c0 = cc * 32;
  int tid = threadIdx.x;
  int r = tid >> 3, q = (tid & 7) * 4;
  const float* src = x2 + ((size_t)b * C2 + (c0 + r)) * NSP + n0 + q;
  float4 v = *reinterpret_cast<const float4*>(src);
  t[r][q] = v.x; t[r][q + 1] = v.y; t[r][q + 2] = v.z; t[r][q + 3] = v.w;
  __syncthreads();
  int l15 = tid & 15, g = (tid >> 4) & 3, sub = tid >> 6;
  int ntl = sub & 1, ih = sub >> 1;
  int nl = ntl * 16 + l15;
  int cl = g * 8 + ih * 4;
  ushort4 o;
  o.x = f2b(t[cl + 0][nl]); o.y = f2b(t[cl + 1][nl]);
  o.z = f2b(t[cl + 2][nl]); o.w = f2b(t[cl + 3][nl]);
  int nt16 = (n0 >> 4) + ntl;
  *reinterpret_cast<ushort4*>(
      x2f + (((size_t)b * 196 + nt16) * 16 + cc) * 512 + (size_t)(tid & 63) * 8 + ih * 4) = o;
}

// ---- K3: MFMA projection GEMM, epilogue writes Kf/Vf frag layouts ------
__global__ __launch_bounds__(256) void k_proj(const ushort* __restrict__ Wf,
    const ushort* __restrict__ x2f, const float* __restrict__ bias,
    ushort* __restrict__ Kf, ushort* __restrict__ Vf) {
  __shared__ __align__(16) ushort WL[2][8][512];
  __shared__ __align__(16) ushort XL[2][4][512];
  int bid = blockIdx.x;      // 784 = 8b * 49nt * 2oh
  int b = bid & 7;
  int tq = bid >> 3;
  int oh = tq & 1;
  int nt = tq >> 1;
  int tid = threadIdx.x;
  int w = tid >> 6, lane = tid & 63, l15 = lane & 15, g = lane >> 4;
  int wq = w >> 1, wn = w & 1;
  int ot0 = oh * 8;
  int nt0 = nt * 4;

  auto stage = [&](int buf, int cc) {
#pragma unroll
    for (int j = 0; j < 3; j++) {
      int chunk = w * 3 + j;
      if (chunk < 8) {
        gload16(Wf + ((size_t)(ot0 + chunk) * 16 + cc) * 512 + lane * 8,
                &WL[buf][chunk][0]);
      } else {
        gload16(x2f + (((size_t)b * 196 + nt0 + (chunk - 8)) * 16 + cc) * 512 + lane * 8,
                &XL[buf][chunk - 8][0]);
      }
    }
  };

  f32x4 zero = {0.f, 0.f, 0.f, 0.f};
  f32x4 acc[4][2];
#pragma unroll
  for (int a = 0; a < 4; a++)
#pragma unroll
    for (int v = 0; v < 2; v++) acc[a][v] = zero;

  stage(0, 0);
  __syncthreads();

  for (int cc = 0; cc < 16; ++cc) {
    int cur = cc & 1;
    if (cc < 15) stage(cur ^ 1, cc + 1);
    bf16x8 A[4], Bf[2];
#pragma unroll
    for (int a = 0; a < 4; a++)
      A[a] = *reinterpret_cast<const bf16x8*>(&WL[cur][wq * 4 + a][lane * 8]);
#pragma unroll
    for (int v = 0; v < 2; v++)
      Bf[v] = *reinterpret_cast<const bf16x8*>(&XL[cur][wn * 2 + v][lane * 8]);
#pragma unroll
    for (int a = 0; a < 4; a++)
#pragma unroll
      for (int v = 0; v < 2; v++)
        acc[a][v] = __builtin_amdgcn_mfma_f32_16x16x32_bf16(A[a], Bf[v], acc[a][v], 0, 0, 0);
    __syncthreads();
  }

  int obase = oh * 128 + wq * 64;
  float4 bias4[4];
#pragma unroll
  for (int a = 0; a < 4; a++)
    bias4[a] = *reinterpret_cast<const float4*>(&bias[obase + a * 16 + g * 4]);

  int gk = (g & 1) * 4;
#pragma unroll
  for (int a = 0; a < 4; a++) {
    int laneK = (((2 * a + (g >> 1)) & 3) << 4) | l15;
    size_t oK = (size_t)(oh * 4 + wq * 2 + (a >> 1));
#pragma unroll
    for (int v = 0; v < 2; v++) {
      int nK = nt * 4 + wn * 2 + v;
      ushort4 st;
      st.x = f2b(acc[a][v][0] + bias4[a].x);
      st.y = f2b(acc[a][v][1] + bias4[a].y);
      st.z = f2b(acc[a][v][2] + bias4[a].z);
      st.w = f2b(acc[a][v][3] + bias4[a].w);
      *reinterpret_cast<ushort4*>(
          Kf + ((((size_t)b * 196 + nK) * 8 + oK) * 64 + laneK) * 8 + gk) = st;
    }
  }
  int nV = nt * 2 + wn;
#pragma unroll
  for (int v = 0; v < 2; v++) {
    int gv = ((v * 2 + (l15 >> 3)) & 3) << 4;
    int iV = l15 & 7;
#pragma unroll
    for (int a = 0; a < 4; a++) {
      int cs = oh * 8 + wq * 4 + a;
      size_t basev = ((((size_t)b * 98 + nV) * 16 + cs) * 64 + gv) * 8 + iV;
      const float* bp4 = reinterpret_cast<const float*>(&bias4[a]);
#pragma unroll
      for (int r = 0; r < 4; r++)
        Vf[basev + (size_t)(g * 4 + r) * 8] = f2b(acc[a][v][r] + bp4[r]);
    }
  }
}

// ---- K4s: balanced-segment flash attention (r7-proven, base-2 sm) ------
// 768 blocks = 8 batches (x = bid&7, XCD-pinned) x 96 segments.
// Scores arrive pre-scaled by log2e (Q scaled in k_x1t) -> exp2f softmax.
__global__ __launch_bounds__(256, 3) void k_attn_s(
    const ushort* __restrict__ x1t, const ushort* __restrict__ Kf,
    const ushort* __restrict__ Vf,
    ushort* __restrict__ Po, float* __restrict__ Mv, float* __restrict__ Lv) {
  __shared__ __align__(16) ushort Kt[2][8192];   // 32KB double-buffered K
  __shared__ __align__(16) ushort Vt[8192];      // 16KB single-buffered V
  __shared__ __align__(16) ushort Plds[4][16][36];
  int bid = blockIdx.x;   // 768
  int x = bid & 7;        // batch <-> XCD affinity
  int j = bid >> 3;       // 0..95
  int s = (4802 * j) / 96;
  int e = (4802 * (j + 1)) / 96;
  int tid = threadIdx.x;
  int w = tid >> 6;
  int lane = tid & 63;
  int l15 = lane & 15;
  int g = lane >> 4;
  int nloc = w * 16 + g * 4;

  const ushort* kg = Kf + (size_t)x * 196 * 8 * 512;
  const ushort* vg = Vf + (size_t)x * 98 * 16 * 512;
  int soff = w * 2048;

  f32x4 zero = {0.f, 0.f, 0.f, 0.f};
  f32x4 O[16];
  f32x4 O17 = zero;
  float M[4];
  bf16x8 qf[8];
  bf16x8 onesf;
#pragma unroll
  for (int i = 0; i < 8; i++) onesf[i] = (short)0x3F80;  // bf16 1.0

  auto resetacc = [&]() {
#pragma unroll
    for (int i = 0; i < 16; i++) O[i] = zero;
    O17 = zero;
#pragma unroll
    for (int r = 0; r < 4; r++) M[r] = -3.0e38f;
  };
  auto loadQ = [&](int u) {
    const ushort* qb = x1t + ((size_t)x * NSP + u * 64 + w * 16 + l15) * C1 + g * 8;
#pragma unroll
    for (int cc = 0; cc < 8; cc++)
      qf[cc] = *reinterpret_cast<const bf16x8*>(qb + cc * 32);
  };

  int u = s / 98;
  int kv = s - u * 98;
  loadQ(u);
  resetacc();
  {
    const ushort* ks = kg + (size_t)kv * 8192 + soff + lane * 8;
#pragma unroll
    for (int jj = 0; jj < 4; ++jj) gload16(ks + jj * 512, &Kt[0][soff] + jj * 512);
  }
  asm volatile("s_waitcnt vmcnt(0)" ::: "memory");
  block_bar();

  int cur = 0;
  for (int i = s; i < e; ++i) {
    // issue V[kv] then (next) K — order matters for counted vmcnt
    {
      const ushort* vs = vg + (size_t)kv * 8192 + soff + lane * 8;
#pragma unroll
      for (int jj = 0; jj < 4; ++jj) gload16(vs + jj * 512, &Vt[soff] + jj * 512);
    }
    asm volatile("" ::: "memory");
    if (i + 1 < e) {
      int kvn = (kv == 97) ? 0 : kv + 1;
      const ushort* ks = kg + (size_t)kvn * 8192 + soff + lane * 8;
#pragma unroll
      for (int jj = 0; jj < 4; ++jj) gload16(ks + jj * 512, &Kt[cur ^ 1][soff] + jj * 512);
    }
    asm volatile("" ::: "memory");

    // ---- S = Q.K^T : 16n x 32m from Kt[cur] ----
    f32x4 s0a = zero, s0b = zero, s1a = zero, s1b = zero;
    const ushort* kb = &Kt[cur][0];
    __builtin_amdgcn_s_setprio(1);
#pragma unroll
    for (int cc = 0; cc < 8; cc += 2) {
      bf16x8 k00 = *reinterpret_cast<const bf16x8*>(kb + ((size_t)cc * 64 + lane) * 8);
      bf16x8 k10 = *reinterpret_cast<const bf16x8*>(kb + ((size_t)(8 + cc) * 64 + lane) * 8);
      bf16x8 k01 = *reinterpret_cast<const bf16x8*>(kb + ((size_t)(cc + 1) * 64 + lane) * 8);
      bf16x8 k11 = *reinterpret_cast<const bf16x8*>(kb + ((size_t)(9 + cc) * 64 + lane) * 8);
      s0a = __builtin_amdgcn_mfma_f32_16x16x32_bf16(qf[cc], k00, s0a, 0, 0, 0);
      s1a = __builtin_amdgcn_mfma_f32_16x16x32_bf16(qf[cc], k10, s1a, 0, 0, 0);
      s0b = __builtin_amdgcn_mfma_f32_16x16x32_bf16(qf[cc + 1], k01, s0b, 0, 0, 0);
      s1b = __builtin_amdgcn_mfma_f32_16x16x32_bf16(qf[cc + 1], k11, s1b, 0, 0, 0);
    }
    __builtin_amdgcn_s_setprio(0);

    // ---- online softmax, base-2, defer-max (THR2 = 8 nats) ----
    float a0[4], a1[4], tmax[4];
#pragma unroll
    for (int r = 0; r < 4; r++) {
      a0[r] = -(s0a[r] + s0b[r]);
      a1[r] = -(s1a[r] + s1b[r]);
      float mx = fmaxf(a0[r], a1[r]);
      mx = fmaxf(mx, __shfl_xor(mx, 1));
      mx = fmaxf(mx, __shfl_xor(mx, 2));
      mx = fmaxf(mx, __shfl_xor(mx, 4));
      mx = fmaxf(mx, __shfl_xor(mx, 8));
      tmax[r] = mx;
    }
    float d01 = fmaxf(tmax[0] - M[0], tmax[1] - M[1]);
    float d23 = fmaxf(tmax[2] - M[2], tmax[3] - M[3]);
    if (__any(fmaxf(d01, d23) > THR2)) {
      float scv[4];
#pragma unroll
      for (int r = 0; r < 4; r++) {
        float nm = fmaxf(M[r], tmax[r]);
        scv[r] = exp2f(M[r] - nm);
        M[r] = nm;
      }
#pragma unroll
      for (int i2 = 0; i2 < 16; i2++) {
#pragma unroll
        for (int r = 0; r < 4; r++) O[i2][r] *= scv[r];
      }
#pragma unroll
      for (int r = 0; r < 4; r++) O17[r] *= scv[r];
    }
#pragma unroll
    for (int r = 0; r < 4; r++) {
      Plds[w][g * 4 + r][l15] = f2b(exp2f(a0[r] - M[r]));
      Plds[w][g * 4 + r][16 + l15] = f2b(exp2f(a1[r] - M[r]));
    }

    // V ready: own 4 newest outstanding are the K-prefetch
    if (i + 1 < e) { asm volatile("s_waitcnt vmcnt(4)" ::: "memory"); }
    else           { asm volatile("s_waitcnt vmcnt(0)" ::: "memory"); }
    block_bar();

    asm volatile("s_waitcnt lgkmcnt(0)" ::: "memory");
    bf16x8 pf = *reinterpret_cast<const bf16x8*>(&Plds[w][l15][g * 8]);
    __builtin_amdgcn_s_setprio(1);
#pragma unroll
    for (int cs = 0; cs < 16; ++cs) {
      bf16x8 vf = *reinterpret_cast<const bf16x8*>(&Vt[0] + ((size_t)cs * 64 + lane) * 8);
      O[cs] = __builtin_amdgcn_mfma_f32_16x16x32_bf16(pf, vf, O[cs], 0, 0, 0);
    }
    O17 = __builtin_amdgcn_mfma_f32_16x16x32_bf16(pf, onesf, O17, 0, 0, 0);
    __builtin_amdgcn_s_setprio(0);

    asm volatile("s_waitcnt vmcnt(0)" ::: "memory");
    block_bar();
    cur ^= 1;

    // ---- piece boundary: flush partial ----
    if ((i + 1 == e) || (kv == 97)) {
      int firstj = (9408 * u + 95) / 4802;       // first segment touching tile u
      int slot = (x * 49 + u) * 3 + (j - firstj);
#pragma unroll
      for (int cs = 0; cs < 16; cs++) {
        int c = cs * 16 + l15;
        ushort4 st;
        st.x = f2b(O[cs][0]); st.y = f2b(O[cs][1]);
        st.z = f2b(O[cs][2]); st.w = f2b(O[cs][3]);
        *reinterpret_cast<ushort4*>(Po + ((size_t)slot * 256 + c) * 64 + nloc) = st;
      }
      if (l15 == 0) {
#pragma unroll
        for (int r = 0; r < 4; r++) {
          Mv[(size_t)slot * 64 + nloc + r] = M[r];
          Lv[(size_t)slot * 64 + nloc + r] = O17[r];
        }
      }
      if (i + 1 < e && kv == 97) { u += 1; loadQ(u); resetacc(); }
    }
    kv = (kv == 97) ? 0 : kv + 1;
  }
}

// ---- K5s: combine <=3 pieces per Q-tile (base-2 M domain) --------------
__global__ __launch_bounds__(256) void k_comb3(
    const ushort* __restrict__ Po, const float* __restrict__ Mv,
    const float* __restrict__ Lv, const float* __restrict__ x1,
    const float* __restrict__ gamma, float* __restrict__ out) {
  int bid = blockIdx.x;     // 8*49
  int x = bid & 7;
  int u = bid >> 3;
  int tid = threadIdx.x;
  int n = tid & 63;
  int c0 = (tid >> 6) * 64;
  int firstj = (9408 * u + 95) / 4802;
  int lastj = (96 * (98 * u + 97) + 95) / 4802;
  int np = lastj - firstj + 1;              // 2 or 3
  size_t base = (size_t)(x * 49 + u) * 3;
  bool has2 = (np >= 3);

  float M0 = Mv[(base + 0) * 64 + n];
  float M1 = Mv[(base + 1) * 64 + n];
  float M2 = has2 ? Mv[(base + 2) * 64 + n] : -3.0e38f;
  float L0 = Lv[(base + 0) * 64 + n];
  float L1 = Lv[(base + 1) * 64 + n];
  float L2 = has2 ? Lv[(base + 2) * 64 + n] : 0.f;
  float Mg = fmaxf(fmaxf(M0, M1), M2);
  float w0 = exp2f(M0 - Mg), w1 = exp2f(M1 - Mg);
  float w2 = has2 ? exp2f(M2 - Mg) : 0.f;
  float rl = gamma[0] / (w0 * L0 + w1 * L1 + w2 * L2);

  const ushort* p0 = Po + ((base + 0) * 256) * 64 + n;
  const ushort* p1 = Po + ((base + 1) * 256) * 64 + n;
  const ushort* p2 = Po + ((base + 2) * 256) * 64 + n;
  size_t ob = (size_t)x * C1 * NSP + u * 64 + n;
#pragma unroll 4
  for (int c = c0; c < c0 + 64; ++c) {
    float acc = w0 * b2f(p0[(size_t)c * 64]) + w1 * b2f(p1[(size_t)c * 64]);
    if (has2) acc += w2 * b2f(p2[(size_t)c * 64]);
    size_t idx = ob + (size_t)c * NSP;
    out[idx] = acc * rl + x1[idx];
  }
}

extern "C" void kernel_launch(void* const* d_in, const int* in_sizes, int n_in,
                              void* d_out, int out_size, void* d_ws, size_t ws_size,
                              hipStream_t stream) {
  const float* x1 = (const float*)d_in[0];
  const float* x2 = (const float*)d_in[1];
  const float* W = (const float*)d_in[2];
  const float* bp = (const float*)d_in[3];
  const float* gamma = (const float*)d_in[4];
  float* out = (float*)d_out;

  char* ws = (char*)d_ws;
  ushort* Wf = (ushort*)(ws + 0);               // 262144
  ushort* x1t = (ushort*)(ws + 262144);         // 12845056
  ushort* Kf = (ushort*)(ws + 13107200);        // 12845056
  ushort* Vf = (ushort*)(ws + 25952256);        // 12845056 -> 38797312
  ushort* Po = (ushort*)(ws + 38797312);        // 1176*256*64*2 = 38535168
  float* Mv = (float*)(ws + 77332480);          // 1176*64*4     =   301056
  float* Lv = (float*)(ws + 77633536);          // 1176*64*4     =   301056
                                                // total            77934592
  // x2f lives in d_out (exact fit): dead after k_proj, before combine.
  ushort* x2f = (ushort*)d_out;                 // 8*196*16*512*2 = 25690112

  k_wtf<<<dim3(16), dim3(256), 0, stream>>>(W, Wf);
  k_x1t<<<dim3(98, 8, 8), dim3(256), 0, stream>>>(x1, x1t);
  k_x2f<<<dim3(98, 16, 8), dim3(256), 0, stream>>>(x2, x2f);
  k_proj<<<dim3(784), dim3(256), 0, stream>>>(Wf, x2f, bp, Kf, Vf);
  k_attn_s<<<dim3(768), dim3(256), 0, stream>>>(x1t, Kf, Vf, Po, Mv, Lv);
  k_comb3<<<dim3(392), dim3(256), 0, stream>>>(Po, Mv, Lv, x1, gamma, out);
}

// Round 12
// 238.546 us; speedup vs baseline: 1.0334x; 1.0334x over previous
//
#include <hip/hip_runtime.h>
#include <hip/hip_bf16.h>

#define C1 256
#define C2 512
#define NSP 3136   // 56*56
#define NT 98      // KV tiles of 32
#define LOG2E 1.44269504f
#define THR2 11.5453f   // 8 nats in base-2 units

typedef __attribute__((ext_vector_type(8))) short bf16x8;
typedef __attribute__((ext_vector_type(4))) float f32x4;

__device__ __forceinline__ ushort f2b(float f) {
  __hip_bfloat16 h = __float2bfloat16(f);
  return *reinterpret_cast<ushort*>(&h);
}
__device__ __forceinline__ float b2f(ushort u) {
  union { unsigned int i; float f; } v; v.i = ((unsigned int)u) << 16; return v.f;
}
__device__ __forceinline__ float fexp2(float x) {
  return __builtin_amdgcn_exp2f(x);   // bare v_exp_f32, no libm guards
}
__device__ __forceinline__ void gload16(const ushort* g, ushort* l) {
  __builtin_amdgcn_global_load_lds(
      (const __attribute__((address_space(1))) void*)g,
      (__attribute__((address_space(3))) void*)l, 16, 0, 0);
}
__device__ __forceinline__ void block_bar() {
  asm volatile("" ::: "memory");
  __builtin_amdgcn_s_barrier();
  asm volatile("" ::: "memory");
}

// ---- K0: Wf[ot16][cc][lane][8] = bf16 A-frag pack of W[o][c] ----------
__global__ __launch_bounds__(256) void k_wtf(const float* __restrict__ W,
                                             ushort* __restrict__ Wf) {
  int ot = blockIdx.x;            // 16
  int tid = threadIdx.x;
  int lane = tid & 63, l15 = lane & 15, g = (lane >> 4) & 3;
  int cc0 = (tid >> 6) * 4;
  const float* src = W + (size_t)(ot * 16 + l15) * C2 + g * 8;
#pragma unroll
  for (int k = 0; k < 4; k++) {
    int cc = cc0 + k;
    float4 u0 = *reinterpret_cast<const float4*>(src + cc * 32);
    float4 u1 = *reinterpret_cast<const float4*>(src + cc * 32 + 4);
    bf16x8 v;
    v[0] = (short)f2b(u0.x); v[1] = (short)f2b(u0.y);
    v[2] = (short)f2b(u0.z); v[3] = (short)f2b(u0.w);
    v[4] = (short)f2b(u1.x); v[5] = (short)f2b(u1.y);
    v[6] = (short)f2b(u1.z); v[7] = (short)f2b(u1.w);
    *reinterpret_cast<bf16x8*>(Wf + ((size_t)(ot * 16 + cc)) * 512 + lane * 8) = v;
  }
}

// ---- K1: x1t[b][n][c] = bf16(LOG2E * x1[b][c][n])  (Q pre-scaled) -----
__global__ __launch_bounds__(256) void k_x1t(const float* __restrict__ x1,
                                             ushort* __restrict__ x1t) {
  __shared__ float t[32][33];
  int b = blockIdx.z;
  int n0 = blockIdx.x * 32;
  int c0 = blockIdx.y * 32;
  int tid = threadIdx.x;
  int r = tid >> 3, q = (tid & 7) * 4;
  const float* src = x1 + ((size_t)b * C1 + (c0 + r)) * NSP + n0 + q;
  float4 v = *reinterpret_cast<const float4*>(src);
  t[r][q] = v.x; t[r][q + 1] = v.y; t[r][q + 2] = v.z; t[r][q + 3] = v.w;
  __syncthreads();
  ushort4 o;
  o.x = f2b(t[q + 0][r] * LOG2E); o.y = f2b(t[q + 1][r] * LOG2E);
  o.z = f2b(t[q + 2][r] * LOG2E); o.w = f2b(t[q + 3][r] * LOG2E);
  *reinterpret_cast<ushort4*>(x1t + ((size_t)b * NSP + n0 + r) * C1 + c0 + q) = o;
}

// ---- K2: x2f[b][nt16][cc][lane][8] = bf16 B-frag pack of x2[b][c][n] --
__global__ __launch_bounds__(256) void k_x2f(const float* __restrict__ x2,
                                             ushort* __restrict__ x2f) {
  __shared__ float t[32][33];
  int b = blockIdx.z;
  int n0 = blockIdx.x * 32;   // 98
  int cc = blockIdx.y;        // 16
  int c0 = cc * 32;
  int tid = threadIdx.x;
  int r = tid >> 3, q = (tid & 7) * 4;
  const float* src = x2 + ((size_t)b * C2 + (c0 + r)) * NSP + n0 + q;
  float4 v = *reinterpret_cast<const float4*>(src);
  t[r][q] = v.x; t[r][q + 1] = v.y; t[r][q + 2] = v.z; t[r][q + 3] = v.w;
  __syncthreads();
  int l15 = tid & 15, g = (tid >> 4) & 3, sub = tid >> 6;
  int ntl = sub & 1, ih = sub >> 1;
  int nl = ntl * 16 + l15;
  int cl = g * 8 + ih * 4;
  ushort4 o;
  o.x = f2b(t[cl + 0][nl]); o.y = f2b(t[cl + 1][nl]);
  o.z = f2b(t[cl + 2][nl]); o.w = f2b(t[cl + 3][nl]);
  int nt16 = (n0 >> 4) + ntl;
  *reinterpret_cast<ushort4*>(
      x2f + (((size_t)b * 196 + nt16) * 16 + cc) * 512 + (size_t)(tid & 63) * 8 + ih * 4) = o;
}

// ---- K3: MFMA projection GEMM, epilogue writes Kf/Vf frag layouts ------
__global__ __launch_bounds__(256) void k_proj(const ushort* __restrict__ Wf,
    const ushort* __restrict__ x2f, const float* __restrict__ bias,
    ushort* __restrict__ Kf, ushort* __restrict__ Vf) {
  __shared__ __align__(16) ushort WL[2][8][512];
  __shared__ __align__(16) ushort XL[2][4][512];
  int bid = blockIdx.x;      // 784 = 8b * 49nt * 2oh
  int b = bid & 7;
  int tq = bid >> 3;
  int oh = tq & 1;
  int nt = tq >> 1;
  int tid = threadIdx.x;
  int w = tid >> 6, lane = tid & 63, l15 = lane & 15, g = lane >> 4;
  int wq = w >> 1, wn = w & 1;
  int ot0 = oh * 8;
  int nt0 = nt * 4;

  auto stage = [&](int buf, int cc) {
#pragma unroll
    for (int j = 0; j < 3; j++) {
      int chunk = w * 3 + j;
      if (chunk < 8) {
        gload16(Wf + ((size_t)(ot0 + chunk) * 16 + cc) * 512 + lane * 8,
                &WL[buf][chunk][0]);
      } else {
        gload16(x2f + (((size_t)b * 196 + nt0 + (chunk - 8)) * 16 + cc) * 512 + lane * 8,
                &XL[buf][chunk - 8][0]);
      }
    }
  };

  f32x4 zero = {0.f, 0.f, 0.f, 0.f};
  f32x4 acc[4][2];
#pragma unroll
  for (int a = 0; a < 4; a++)
#pragma unroll
    for (int v = 0; v < 2; v++) acc[a][v] = zero;

  stage(0, 0);
  __syncthreads();

  for (int cc = 0; cc < 16; ++cc) {
    int cur = cc & 1;
    if (cc < 15) stage(cur ^ 1, cc + 1);
    bf16x8 A[4], Bf[2];
#pragma unroll
    for (int a = 0; a < 4; a++)
      A[a] = *reinterpret_cast<const bf16x8*>(&WL[cur][wq * 4 + a][lane * 8]);
#pragma unroll
    for (int v = 0; v < 2; v++)
      Bf[v] = *reinterpret_cast<const bf16x8*>(&XL[cur][wn * 2 + v][lane * 8]);
#pragma unroll
    for (int a = 0; a < 4; a++)
#pragma unroll
      for (int v = 0; v < 2; v++)
        acc[a][v] = __builtin_amdgcn_mfma_f32_16x16x32_bf16(A[a], Bf[v], acc[a][v], 0, 0, 0);
    __syncthreads();
  }

  int obase = oh * 128 + wq * 64;
  float4 bias4[4];
#pragma unroll
  for (int a = 0; a < 4; a++)
    bias4[a] = *reinterpret_cast<const float4*>(&bias[obase + a * 16 + g * 4]);

  int gk = (g & 1) * 4;
#pragma unroll
  for (int a = 0; a < 4; a++) {
    int laneK = (((2 * a + (g >> 1)) & 3) << 4) | l15;
    size_t oK = (size_t)(oh * 4 + wq * 2 + (a >> 1));
#pragma unroll
    for (int v = 0; v < 2; v++) {
      int nK = nt * 4 + wn * 2 + v;
      ushort4 st;
      st.x = f2b(acc[a][v][0] + bias4[a].x);
      st.y = f2b(acc[a][v][1] + bias4[a].y);
      st.z = f2b(acc[a][v][2] + bias4[a].z);
      st.w = f2b(acc[a][v][3] + bias4[a].w);
      *reinterpret_cast<ushort4*>(
          Kf + ((((size_t)b * 196 + nK) * 8 + oK) * 64 + laneK) * 8 + gk) = st;
    }
  }
  int nV = nt * 2 + wn;
#pragma unroll
  for (int v = 0; v < 2; v++) {
    int gv = ((v * 2 + (l15 >> 3)) & 3) << 4;
    int iV = l15 & 7;
#pragma unroll
    for (int a = 0; a < 4; a++) {
      int cs = oh * 8 + wq * 4 + a;
      size_t basev = ((((size_t)b * 98 + nV) * 16 + cs) * 64 + gv) * 8 + iV;
      const float* bp4 = reinterpret_cast<const float*>(&bias4[a]);
#pragma unroll
      for (int r = 0; r < 4; r++)
        Vf[basev + (size_t)(g * 4 + r) * 8] = f2b(acc[a][v][r] + bp4[r]);
    }
  }
}

// ---- K4s: balanced-segment flash attention (r7-proven, base-2 sm) ------
// 768 blocks = 8 batches (x = bid&7, XCD-pinned) x 96 segments.
// Scores arrive pre-scaled by log2e (Q scaled in k_x1t) -> v_exp_f32 softmax.
__global__ __launch_bounds__(256, 3) void k_attn_s(
    const ushort* __restrict__ x1t, const ushort* __restrict__ Kf,
    const ushort* __restrict__ Vf,
    ushort* __restrict__ Po, float* __restrict__ Mv, float* __restrict__ Lv) {
  __shared__ __align__(16) ushort Kt[2][8192];   // 32KB double-buffered K
  __shared__ __align__(16) ushort Vt[8192];      // 16KB single-buffered V
  __shared__ __align__(16) ushort Plds[4][16][36];
  int bid = blockIdx.x;   // 768
  int x = bid & 7;        // batch <-> XCD affinity
  int j = bid >> 3;       // 0..95
  int s = (4802 * j) / 96;
  int e = (4802 * (j + 1)) / 96;
  int tid = threadIdx.x;
  int w = tid >> 6;
  int lane = tid & 63;
  int l15 = lane & 15;
  int g = lane >> 4;
  int nloc = w * 16 + g * 4;

  const ushort* kg = Kf + (size_t)x * 196 * 8 * 512;
  const ushort* vg = Vf + (size_t)x * 98 * 16 * 512;
  int soff = w * 2048;

  f32x4 zero = {0.f, 0.f, 0.f, 0.f};
  f32x4 O[16];
  f32x4 O17 = zero;
  float M[4];
  bf16x8 qf[8];
  bf16x8 onesf;
#pragma unroll
  for (int i = 0; i < 8; i++) onesf[i] = (short)0x3F80;  // bf16 1.0

  auto resetacc = [&]() {
#pragma unroll
    for (int i = 0; i < 16; i++) O[i] = zero;
    O17 = zero;
#pragma unroll
    for (int r = 0; r < 4; r++) M[r] = -3.0e38f;
  };
  auto loadQ = [&](int u) {
    const ushort* qb = x1t + ((size_t)x * NSP + u * 64 + w * 16 + l15) * C1 + g * 8;
#pragma unroll
    for (int cc = 0; cc < 8; cc++)
      qf[cc] = *reinterpret_cast<const bf16x8*>(qb + cc * 32);
  };

  int u = s / 98;
  int kv = s - u * 98;
  loadQ(u);
  resetacc();
  {
    const ushort* ks = kg + (size_t)kv * 8192 + soff + lane * 8;
#pragma unroll
    for (int jj = 0; jj < 4; ++jj) gload16(ks + jj * 512, &Kt[0][soff] + jj * 512);
  }
  asm volatile("s_waitcnt vmcnt(0)" ::: "memory");
  block_bar();

  int cur = 0;
  for (int i = s; i < e; ++i) {
    // issue V[kv] then (next) K — order matters for counted vmcnt
    {
      const ushort* vs = vg + (size_t)kv * 8192 + soff + lane * 8;
#pragma unroll
      for (int jj = 0; jj < 4; ++jj) gload16(vs + jj * 512, &Vt[soff] + jj * 512);
    }
    asm volatile("" ::: "memory");
    if (i + 1 < e) {
      int kvn = (kv == 97) ? 0 : kv + 1;
      const ushort* ks = kg + (size_t)kvn * 8192 + soff + lane * 8;
#pragma unroll
      for (int jj = 0; jj < 4; ++jj) gload16(ks + jj * 512, &Kt[cur ^ 1][soff] + jj * 512);
    }
    asm volatile("" ::: "memory");

    // ---- S = Q.K^T : 16n x 32m from Kt[cur] ----
    f32x4 s0a = zero, s0b = zero, s1a = zero, s1b = zero;
    const ushort* kb = &Kt[cur][0];
    __builtin_amdgcn_s_setprio(1);
#pragma unroll
    for (int cc = 0; cc < 8; cc += 2) {
      bf16x8 k00 = *reinterpret_cast<const bf16x8*>(kb + ((size_t)cc * 64 + lane) * 8);
      bf16x8 k10 = *reinterpret_cast<const bf16x8*>(kb + ((size_t)(8 + cc) * 64 + lane) * 8);
      bf16x8 k01 = *reinterpret_cast<const bf16x8*>(kb + ((size_t)(cc + 1) * 64 + lane) * 8);
      bf16x8 k11 = *reinterpret_cast<const bf16x8*>(kb + ((size_t)(9 + cc) * 64 + lane) * 8);
      s0a = __builtin_amdgcn_mfma_f32_16x16x32_bf16(qf[cc], k00, s0a, 0, 0, 0);
      s1a = __builtin_amdgcn_mfma_f32_16x16x32_bf16(qf[cc], k10, s1a, 0, 0, 0);
      s0b = __builtin_amdgcn_mfma_f32_16x16x32_bf16(qf[cc + 1], k01, s0b, 0, 0, 0);
      s1b = __builtin_amdgcn_mfma_f32_16x16x32_bf16(qf[cc + 1], k11, s1b, 0, 0, 0);
    }
    __builtin_amdgcn_s_setprio(0);

    // ---- online softmax, base-2, defer-max (THR2 = 8 nats) ----
    float a0[4], a1[4], tmax[4];
#pragma unroll
    for (int r = 0; r < 4; r++) {
      a0[r] = -(s0a[r] + s0b[r]);
      a1[r] = -(s1a[r] + s1b[r]);
      float mx = fmaxf(a0[r], a1[r]);
      mx = fmaxf(mx, __shfl_xor(mx, 1));
      mx = fmaxf(mx, __shfl_xor(mx, 2));
      mx = fmaxf(mx, __shfl_xor(mx, 4));
      mx = fmaxf(mx, __shfl_xor(mx, 8));
      tmax[r] = mx;
    }
    float d01 = fmaxf(tmax[0] - M[0], tmax[1] - M[1]);
    float d23 = fmaxf(tmax[2] - M[2], tmax[3] - M[3]);
    if (__any(fmaxf(d01, d23) > THR2)) {
      float scv[4];
#pragma unroll
      for (int r = 0; r < 4; r++) {
        float nm = fmaxf(M[r], tmax[r]);
        scv[r] = fexp2(M[r] - nm);
        M[r] = nm;
      }
#pragma unroll
      for (int i2 = 0; i2 < 16; i2++) {
#pragma unroll
        for (int r = 0; r < 4; r++) O[i2][r] *= scv[r];
      }
#pragma unroll
      for (int r = 0; r < 4; r++) O17[r] *= scv[r];
    }
#pragma unroll
    for (int r = 0; r < 4; r++) {
      Plds[w][g * 4 + r][l15] = f2b(fexp2(a0[r] - M[r]));
      Plds[w][g * 4 + r][16 + l15] = f2b(fexp2(a1[r] - M[r]));
    }

    // V ready: own 4 newest outstanding are the K-prefetch
    if (i + 1 < e) { asm volatile("s_waitcnt vmcnt(4)" ::: "memory"); }
    else           { asm volatile("s_waitcnt vmcnt(0)" ::: "memory"); }
    block_bar();

    asm volatile("s_waitcnt lgkmcnt(0)" ::: "memory");
    bf16x8 pf = *reinterpret_cast<const bf16x8*>(&Plds[w][l15][g * 8]);
    __builtin_amdgcn_s_setprio(1);
#pragma unroll
    for (int cs = 0; cs < 16; ++cs) {
      bf16x8 vf = *reinterpret_cast<const bf16x8*>(&Vt[0] + ((size_t)cs * 64 + lane) * 8);
      O[cs] = __builtin_amdgcn_mfma_f32_16x16x32_bf16(pf, vf, O[cs], 0, 0, 0);
    }
    O17 = __builtin_amdgcn_mfma_f32_16x16x32_bf16(pf, onesf, O17, 0, 0, 0);
    __builtin_amdgcn_s_setprio(0);

    asm volatile("s_waitcnt vmcnt(0)" ::: "memory");
    block_bar();
    cur ^= 1;

    // ---- piece boundary: flush partial ----
    if ((i + 1 == e) || (kv == 97)) {
      int firstj = (9408 * u + 95) / 4802;       // first segment touching tile u
      int slot = (x * 49 + u) * 3 + (j - firstj);
#pragma unroll
      for (int cs = 0; cs < 16; cs++) {
        int c = cs * 16 + l15;
        ushort4 st;
        st.x = f2b(O[cs][0]); st.y = f2b(O[cs][1]);
        st.z = f2b(O[cs][2]); st.w = f2b(O[cs][3]);
        *reinterpret_cast<ushort4*>(Po + ((size_t)slot * 256 + c) * 64 + nloc) = st;
      }
      if (l15 == 0) {
#pragma unroll
        for (int r = 0; r < 4; r++) {
          Mv[(size_t)slot * 64 + nloc + r] = M[r];
          Lv[(size_t)slot * 64 + nloc + r] = O17[r];
        }
      }
      if (i + 1 < e && kv == 97) { u += 1; loadQ(u); resetacc(); }
    }
    kv = (kv == 97) ? 0 : kv + 1;
  }
}

// ---- K5s: combine <=3 pieces per Q-tile (base-2 M domain) --------------
__global__ __launch_bounds__(256) void k_comb3(
    const ushort* __restrict__ Po, const float* __restrict__ Mv,
    const float* __restrict__ Lv, const float* __restrict__ x1,
    const float* __restrict__ gamma, float* __restrict__ out) {
  int bid = blockIdx.x;     // 8*49
  int x = bid & 7;
  int u = bid >> 3;
  int tid = threadIdx.x;
  int n = tid & 63;
  int c0 = (tid >> 6) * 64;
  int firstj = (9408 * u + 95) / 4802;
  int lastj = (96 * (98 * u + 97) + 95) / 4802;
  int np = lastj - firstj + 1;              // 2 or 3
  size_t base = (size_t)(x * 49 + u) * 3;
  bool has2 = (np >= 3);

  float M0 = Mv[(base + 0) * 64 + n];
  float M1 = Mv[(base + 1) * 64 + n];
  float M2 = has2 ? Mv[(base + 2) * 64 + n] : -3.0e38f;
  float L0 = Lv[(base + 0) * 64 + n];
  float L1 = Lv[(base + 1) * 64 + n];
  float L2 = has2 ? Lv[(base + 2) * 64 + n] : 0.f;
  float Mg = fmaxf(fmaxf(M0, M1), M2);
  float w0 = fexp2(M0 - Mg), w1 = fexp2(M1 - Mg);
  float w2 = has2 ? fexp2(M2 - Mg) : 0.f;
  float rl = gamma[0] / (w0 * L0 + w1 * L1 + w2 * L2);

  const ushort* p0 = Po + ((base + 0) * 256) * 64 + n;
  const ushort* p1 = Po + ((base + 1) * 256) * 64 + n;
  const ushort* p2 = Po + ((base + 2) * 256) * 64 + n;
  size_t ob = (size_t)x * C1 * NSP + u * 64 + n;
#pragma unroll 4
  for (int c = c0; c < c0 + 64; ++c) {
    float acc = w0 * b2f(p0[(size_t)c * 64]) + w1 * b2f(p1[(size_t)c * 64]);
    if (has2) acc += w2 * b2f(p2[(size_t)c * 64]);
    size_t idx = ob + (size_t)c * NSP;
    out[idx] = acc * rl + x1[idx];
  }
}

extern "C" void kernel_launch(void* const* d_in, const int* in_sizes, int n_in,
                              void* d_out, int out_size, void* d_ws, size_t ws_size,
                              hipStream_t stream) {
  const float* x1 = (const float*)d_in[0];
  const float* x2 = (const float*)d_in[1];
  const float* W = (const float*)d_in[2];
  const float* bp = (const float*)d_in[3];
  const float* gamma = (const float*)d_in[4];
  float* out = (float*)d_out;

  char* ws = (char*)d_ws;
  ushort* Wf = (ushort*)(ws + 0);               // 262144
  ushort* x1t = (ushort*)(ws + 262144);         // 12845056
  ushort* Kf = (ushort*)(ws + 13107200);        // 12845056
  ushort* Vf = (ushort*)(ws + 25952256);        // 12845056 -> 38797312
  ushort* Po = (ushort*)(ws + 38797312);        // 1176*256*64*2 = 38535168
  float* Mv = (float*)(ws + 77332480);          // 1176*64*4     =   301056
  float* Lv = (float*)(ws + 77633536);          // 1176*64*4     =   301056
                                                // total            77934592
  // x2f lives in d_out (exact fit): dead after k_proj, before combine.
  ushort* x2f = (ushort*)d_out;                 // 8*196*16*512*2 = 25690112

  k_wtf<<<dim3(16), dim3(256), 0, stream>>>(W, Wf);
  k_x1t<<<dim3(98, 8, 8), dim3(256), 0, stream>>>(x1, x1t);
  k_x2f<<<dim3(98, 16, 8), dim3(256), 0, stream>>>(x2, x2f);
  k_proj<<<dim3(784), dim3(256), 0, stream>>>(Wf, x2f, bp, Kf, Vf);
  k_attn_s<<<dim3(768), dim3(256), 0, stream>>>(x1t, Kf, Vf, Po, Mv, Lv);
  k_comb3<<<dim3(392), dim3(256), 0, stream>>>(Po, Mv, Lv, x1, gamma, out);
}